// Round 16
// baseline (36.268 us; speedup 1.0000x reference)
//
#include <hip/hip_runtime.h>

#define NBINS 10
#define NG 4
#define NH (NG * NBINS)      // 40
#define TPB 128              // 2 waves; each thread owns a private LDS column
#define NBLOCKS 2048         // 8 blocks/CU * 256 CU; LDS 20KB -> exactly 8/CU
#define REPEAT 2             // MEASUREMENT: process input twice; h-normalization
                             // cancels the 2x count scale (offset shift ~5e-5 rel)
#define PACKF 128.0f         // acc = 128*n + U; n<=70, U<128 -> exact unpack

typedef float f32x4 __attribute__((ext_vector_type(4)));
typedef int   i32x4 __attribute__((ext_vector_type(4)));

// Single packed LDS RMW per sample. With pitch == radius (0.1):
//   h[j] ∝ n_j - U_j + U_{j-1},  n_j = #{floor-bin==j}, U_j = sum(u),
// where p = 10*(sigmoid(x)-1e-4), j0 = floor(p), u = p - j0 in [0,1).
// Column layout: addr = row*TPB + tid -> bank = tid%32, 2 lanes/bank per
// wave = conflict-free (free per m136).
__device__ __forceinline__ void proc1(float x, int g, float* col) {
    float ex = __expf(-x);
    float rc = __builtin_amdgcn_rcpf(1.0f + ex);
    float p  = __builtin_fmaf(rc, 10.0f, -0.001f);
    float fj = floorf(p);
    float u  = p - fj;
    int j0 = max((int)fj, 0);
    col[(g * NBINS + j0) * TPB] += (PACKF + u);
}

__global__ void __launch_bounds__(TPB, 4) wb_hist(const f32x4* __restrict__ acts,
                                                  const i32x4* __restrict__ labels,
                                                  const float* __restrict__ acts_s,
                                                  const int* __restrict__ labels_s,
                                                  float* __restrict__ parts,
                                                  int n4, int n, int nparts) {
    __shared__ float lh[NH * TPB];          // exactly 20 KB -> 8 blocks/CU
    const int tid = threadIdx.x;
    #pragma unroll
    for (int i = 0; i < NH; ++i) lh[i * TPB + tid] = 0.0f;
    __syncthreads();

    float* col = &lh[tid];

    for (int rep = 0; rep < REPEAT; ++rep) {
        if (n4 == NBLOCKS * TPB * 8) {
            // ---- PHASE-SPLIT path (benchmark shape: 32 samples/thread) ----
            const int base = blockIdx.x * (TPB * 8) + tid;
            f32x4 a[8]; i32x4 g[8];
            #pragma unroll
            for (int k = 0; k < 8; ++k) a[k] = __builtin_nontemporal_load(&acts[base + k * TPB]);
            #pragma unroll
            for (int k = 0; k < 8; ++k) g[k] = __builtin_nontemporal_load(&labels[base + k * TPB]);

            float uu[32]; int rr[32];
            #pragma unroll
            for (int k = 0; k < 8; ++k) {
                #pragma unroll
                for (int e = 0; e < 4; ++e) {
                    float x = a[k][e];
                    float ex = __expf(-x);
                    float rc = __builtin_amdgcn_rcpf(1.0f + ex);
                    float p  = __builtin_fmaf(rc, 10.0f, -0.001f);
                    float fj = floorf(p);
                    uu[k * 4 + e] = p - fj;
                    rr[k * 4 + e] = g[k][e] * NBINS + max((int)fj, 0);
                }
            }
            #pragma unroll
            for (int s = 0; s < 32; ++s)
                col[rr[s] * TPB] += (PACKF + uu[s]);
        } else {
            // generic fallback: strided NT batch loop
            const int gsz = gridDim.x * TPB;
            int idx = blockIdx.x * TPB + tid;
            for (; idx + 3 * gsz < n4; idx += 4 * gsz) {
                f32x4 a0 = __builtin_nontemporal_load(&acts[idx]);
                f32x4 a1 = __builtin_nontemporal_load(&acts[idx + gsz]);
                f32x4 a2 = __builtin_nontemporal_load(&acts[idx + 2 * gsz]);
                f32x4 a3 = __builtin_nontemporal_load(&acts[idx + 3 * gsz]);
                i32x4 g0 = __builtin_nontemporal_load(&labels[idx]);
                i32x4 g1 = __builtin_nontemporal_load(&labels[idx + gsz]);
                i32x4 g2 = __builtin_nontemporal_load(&labels[idx + 2 * gsz]);
                i32x4 g3 = __builtin_nontemporal_load(&labels[idx + 3 * gsz]);
                #pragma unroll
                for (int e = 0; e < 4; ++e) proc1(a0[e], g0[e], col);
                #pragma unroll
                for (int e = 0; e < 4; ++e) proc1(a1[e], g1[e], col);
                #pragma unroll
                for (int e = 0; e < 4; ++e) proc1(a2[e], g2[e], col);
                #pragma unroll
                for (int e = 0; e < 4; ++e) proc1(a3[e], g3[e], col);
            }
            for (; idx < n4; idx += gsz) {
                f32x4 a = __builtin_nontemporal_load(&acts[idx]);
                i32x4 g = __builtin_nontemporal_load(&labels[idx]);
                #pragma unroll
                for (int e = 0; e < 4; ++e) proc1(a[e], g[e], col);
            }
        }

        // scalar tail for N % 4 != 0 (not hit for N = 8388608); inside rep
        // loop so tail samples get the same x2 weight (scale cancels in norm)
        if (blockIdx.x == 0 && tid == 0) {
            for (int i = n4 * 4; i < n; ++i) proc1(acts_s[i], labels_s[i], col);
        }
        asm volatile("" ::: "memory");   // force real reloads on pass 2
    }
    __syncthreads();

    // Per-block epilogue: unpack columns (n = floor(acc/128), U = acc - 128n),
    // fold U_{j-1} in via shfl_up (rows 0..39 live in wave 0), write direct
    // (2x-scaled) histogram contribution. No atomics, no fences.
    if (tid < NH) {
        float n_sum = 0.0f, u_sum = 0.0f;
        for (int k = 0; k < TPB; ++k) {     // skewed start: <=2-way bank alias
            float acc = lh[tid * TPB + ((tid + k) & (TPB - 1))];
            float nc = floorf(acc * (1.0f / PACKF));
            n_sum += nc;
            u_sum += acc - PACKF * nc;
        }
        float u_prev = __shfl_up(u_sum, 1);
        if ((tid % NBINS) == 0) u_prev = 0.0f;
        parts[tid * nparts + blockIdx.x] = 0.1f * (n_sum - u_sum + u_prev);
    }
}

__global__ void __launch_bounds__(1024) wb_final(const float4* __restrict__ parts4,
                                                 const float* __restrict__ bary,
                                                 float* __restrict__ out, int nparts) {
    __shared__ float hist[NH];
    __shared__ float bsh[NBINS];
    __shared__ float losses[NG];

    if (threadIdx.x < NBINS) {
        float b = bary[threadIdx.x];
        bsh[threadIdx.x] = b;
        out[1 + threadIdx.x] = b;     // tuple output: bary_est passthrough
    }

    // float4 reduce of [40][nparts] partials: each float4 = 4 partials, same bin
    const int q4 = nparts >> 2;
    int wave = threadIdx.x >> 6, lane = threadIdx.x & 63;
    for (int j = wave; j < NH; j += 16) {
        float s = 0.0f;
        for (int i = lane; i < q4; i += 64) {
            float4 v = parts4[j * q4 + i];
            s += (v.x + v.y) + (v.z + v.w);
        }
        #pragma unroll
        for (int off = 32; off; off >>= 1) s += __shfl_down(s, off);
        if (lane == 0) hist[j] = s;
    }
    __syncthreads();

    // 4 lanes (one per group); the 2x count scale cancels in h/sum(h)
    if (threadIdx.x < NG) {
        const int gI = threadIdx.x;
        float h[NBINS];
        float s = 0.0f;
        #pragma unroll
        for (int j = 0; j < NBINS; ++j) { h[j] = hist[gI * NBINS + j] + 0.0001f; s += h[j]; }
        #pragma unroll
        for (int j = 0; j < NBINS; ++j) h[j] /= s;
        float s2 = 0.0f;                    // genHists renorm (fp no-op, kept for fidelity)
        #pragma unroll
        for (int j = 0; j < NBINS; ++j) s2 += h[j];
        #pragma unroll
        for (int j = 0; j < NBINS; ++j) h[j] /= s2;

        float cdfa[NBINS], cdfb[NBINS];
        float acc = 0.0f;
        #pragma unroll
        for (int j = 0; j < NBINS; ++j) { acc += h[j]; cdfa[j] = acc; }
        acc = 0.0f;
        #pragma unroll
        for (int j = 0; j < NBINS; ++j) { acc += bsh[j]; cdfb[j] = acc; }
        // top-equalization reproduces searchsorted clip at q > min(top_a, top_b)
        float T = fmaxf(cdfa[NBINS - 1], cdfb[NBINS - 1]);
        cdfa[NBINS - 1] = T;
        cdfb[NBINS - 1] = T;

        // sum over merged quantile intervals == sum of pairwise interval overlaps
        float loss = 0.0f, lo_a = 0.0f;
        #pragma unroll
        for (int i = 0; i < NBINS; ++i) {
            float hi_a = cdfa[i];
            float lo_b = 0.0f;
            #pragma unroll
            for (int j = 0; j < NBINS; ++j) {
                float hi_b = cdfb[j];
                float ov = fminf(hi_a, hi_b) - fmaxf(lo_a, lo_b);
                float w = (float)((i - j) * (i - j));
                loss += fmaxf(ov, 0.0f) * w;
                lo_b = hi_b;
            }
            lo_a = hi_a;
        }
        losses[gI] = loss;
    }
    __syncthreads();
    if (threadIdx.x == 0)
        out[0] = losses[0] + losses[1] + losses[2] + losses[3];
}

extern "C" void kernel_launch(void* const* d_in, const int* in_sizes, int n_in,
                              void* d_out, int out_size, void* d_ws, size_t ws_size,
                              hipStream_t stream) {
    const float* acts   = (const float*)d_in[0];
    const float* bary   = (const float*)d_in[1];
    const int*   labels = (const int*)d_in[2];
    float* outp  = (float*)d_out;
    float* parts = (float*)d_ws;           // [NH][NBLOCKS] = 327 KB, fully rewritten
    int N  = in_sizes[0];
    int n4 = N >> 2;

    wb_hist<<<NBLOCKS, TPB, 0, stream>>>((const f32x4*)acts, (const i32x4*)labels,
                                         acts, labels, parts, n4, N, NBLOCKS);
    wb_final<<<1, 1024, 0, stream>>>((const float4*)parts, bary, outp, NBLOCKS);
}

// Round 17
// 29.570 us; speedup vs baseline: 1.2265x; 1.2265x over previous
//
#include <hip/hip_runtime.h>

#define NBINS 10
#define NG 4
#define NH (NG * NBINS)      // 40
#define TPB 128              // 2 waves; each thread owns a private LDS column
#define NBLOCKS 2048         // 8 blocks/CU * 256 CU; LDS 20KB -> exactly 8/CU
#define PACKF 32.0f          // acc = 32*n + U; n<=32/column, U<32 -> exact unpack

typedef float f32x4 __attribute__((ext_vector_type(4)));
typedef int   i32x4 __attribute__((ext_vector_type(4)));

// Single packed LDS RMW per sample. With pitch == radius (0.1):
//   h[j] = 0.1*(n_j - U_j + U_{j-1}),  n_j = #{floor-bin==j}, U_j = sum(u),
// where p = 10*(sigmoid(x)-1e-4), j0 = floor(p), u = p - j0 in [0,1).
// Column layout: addr = row*TPB + tid -> bank = tid%32, 2 lanes/bank per
// wave = conflict-free (free per m136).
__device__ __forceinline__ void proc1(float x, int g, float* col) {
    float ex = __expf(-x);
    float rc = __builtin_amdgcn_rcpf(1.0f + ex);
    float p  = __builtin_fmaf(rc, 10.0f, -0.001f);
    float fj = floorf(p);
    float u  = p - fj;
    int j0 = max((int)fj, 0);
    col[(g * NBINS + j0) * TPB] += (PACKF + u);
}

__global__ void __launch_bounds__(TPB, 4) wb_hist(const f32x4* __restrict__ acts,
                                                  const i32x4* __restrict__ labels,
                                                  const float* __restrict__ acts_s,
                                                  const int* __restrict__ labels_s,
                                                  float* __restrict__ parts,
                                                  int n4, int n, int nparts) {
    __shared__ float lh[NH * TPB];          // exactly 20 KB -> 8 blocks/CU
    const int tid = threadIdx.x;
    #pragma unroll
    for (int i = 0; i < NH; ++i) lh[i * TPB + tid] = 0.0f;
    __syncthreads();

    float* col = &lh[tid];

    if (n4 == NBLOCKS * TPB * 8) {
        // ---- PHASE-SPLIT path (benchmark shape: 32 samples/thread) ----
        // Phase 1: all 16 NT loads (contiguous 16 KB run per array per block;
        // read-once stream bypasses cache allocation).
        const int base = blockIdx.x * (TPB * 8) + tid;
        f32x4 a[8]; i32x4 g[8];
        #pragma unroll
        for (int k = 0; k < 8; ++k) a[k] = __builtin_nontemporal_load(&acts[base + k * TPB]);
        #pragma unroll
        for (int k = 0; k < 8; ++k) g[k] = __builtin_nontemporal_load(&labels[base + k * TPB]);

        // Phase 2: pure-VALU burst -> static register arrays (no DS ops, so
        // all of this issues while the loads drain; one vmcnt wait total).
        float uu[32]; int rr[32];
        #pragma unroll
        for (int k = 0; k < 8; ++k) {
            #pragma unroll
            for (int e = 0; e < 4; ++e) {
                float x = a[k][e];
                float ex = __expf(-x);
                float rc = __builtin_amdgcn_rcpf(1.0f + ex);
                float p  = __builtin_fmaf(rc, 10.0f, -0.001f);
                float fj = floorf(p);
                uu[k * 4 + e] = p - fj;
                rr[k * 4 + e] = g[k][e] * NBINS + max((int)fj, 0);
            }
        }

        // Phase 3: tight LDS RMW burst; lgkmcnt stalls overlap with other
        // waves' phase-1/2 (waves desynchronize across the CU).
        #pragma unroll
        for (int s = 0; s < 32; ++s)
            col[rr[s] * TPB] += (PACKF + uu[s]);
    } else {
        // generic fallback: strided NT batch loop
        const int gsz = gridDim.x * TPB;
        int idx = blockIdx.x * TPB + tid;
        for (; idx + 3 * gsz < n4; idx += 4 * gsz) {
            f32x4 a0 = __builtin_nontemporal_load(&acts[idx]);
            f32x4 a1 = __builtin_nontemporal_load(&acts[idx + gsz]);
            f32x4 a2 = __builtin_nontemporal_load(&acts[idx + 2 * gsz]);
            f32x4 a3 = __builtin_nontemporal_load(&acts[idx + 3 * gsz]);
            i32x4 g0 = __builtin_nontemporal_load(&labels[idx]);
            i32x4 g1 = __builtin_nontemporal_load(&labels[idx + gsz]);
            i32x4 g2 = __builtin_nontemporal_load(&labels[idx + 2 * gsz]);
            i32x4 g3 = __builtin_nontemporal_load(&labels[idx + 3 * gsz]);
            #pragma unroll
            for (int e = 0; e < 4; ++e) proc1(a0[e], g0[e], col);
            #pragma unroll
            for (int e = 0; e < 4; ++e) proc1(a1[e], g1[e], col);
            #pragma unroll
            for (int e = 0; e < 4; ++e) proc1(a2[e], g2[e], col);
            #pragma unroll
            for (int e = 0; e < 4; ++e) proc1(a3[e], g3[e], col);
        }
        for (; idx < n4; idx += gsz) {
            f32x4 a = __builtin_nontemporal_load(&acts[idx]);
            i32x4 g = __builtin_nontemporal_load(&labels[idx]);
            #pragma unroll
            for (int e = 0; e < 4; ++e) proc1(a[e], g[e], col);
        }
    }

    // scalar tail for N % 4 != 0 (not hit for N = 8388608)
    if (blockIdx.x == 0 && tid == 0) {
        for (int i = n4 * 4; i < n; ++i) proc1(acts_s[i], labels_s[i], col);
    }
    __syncthreads();

    // Per-block epilogue: unpack columns (n = floor(acc/32), U = acc - 32n),
    // fold U_{j-1} in via shfl_up (rows 0..39 live in wave 0), write direct
    // histogram contribution. No atomics, no fences.
    if (tid < NH) {
        float n_sum = 0.0f, u_sum = 0.0f;
        for (int k = 0; k < TPB; ++k) {     // skewed start: <=2-way bank alias
            float acc = lh[tid * TPB + ((tid + k) & (TPB - 1))];
            float nc = floorf(acc * (1.0f / PACKF));
            n_sum += nc;
            u_sum += acc - PACKF * nc;
        }
        float u_prev = __shfl_up(u_sum, 1);
        if ((tid % NBINS) == 0) u_prev = 0.0f;
        parts[tid * nparts + blockIdx.x] = 0.1f * (n_sum - u_sum + u_prev);
    }
}

__global__ void __launch_bounds__(1024) wb_final(const float4* __restrict__ parts4,
                                                 const float* __restrict__ bary,
                                                 float* __restrict__ out, int nparts) {
    __shared__ float hist[NH];
    __shared__ float bsh[NBINS];
    __shared__ float losses[NG];

    if (threadIdx.x < NBINS) {
        float b = bary[threadIdx.x];
        bsh[threadIdx.x] = b;
        out[1 + threadIdx.x] = b;     // tuple output: bary_est passthrough
    }

    // float4 reduce of [40][nparts] partials: each float4 = 4 partials, same bin
    const int q4 = nparts >> 2;
    int wave = threadIdx.x >> 6, lane = threadIdx.x & 63;
    for (int j = wave; j < NH; j += 16) {
        float s = 0.0f;
        for (int i = lane; i < q4; i += 64) {
            float4 v = parts4[j * q4 + i];
            s += (v.x + v.y) + (v.z + v.w);
        }
        #pragma unroll
        for (int off = 32; off; off >>= 1) s += __shfl_down(s, off);
        if (lane == 0) hist[j] = s;
    }
    __syncthreads();

    // 4 lanes (one per group), uniform control flow, all arrays register-resident
    if (threadIdx.x < NG) {
        const int gI = threadIdx.x;
        float h[NBINS];
        float s = 0.0f;
        #pragma unroll
        for (int j = 0; j < NBINS; ++j) { h[j] = hist[gI * NBINS + j] + 0.0001f; s += h[j]; }
        #pragma unroll
        for (int j = 0; j < NBINS; ++j) h[j] /= s;
        float s2 = 0.0f;                    // genHists renorm (fp no-op, kept for fidelity)
        #pragma unroll
        for (int j = 0; j < NBINS; ++j) s2 += h[j];
        #pragma unroll
        for (int j = 0; j < NBINS; ++j) h[j] /= s2;

        float cdfa[NBINS], cdfb[NBINS];
        float acc = 0.0f;
        #pragma unroll
        for (int j = 0; j < NBINS; ++j) { acc += h[j]; cdfa[j] = acc; }
        acc = 0.0f;
        #pragma unroll
        for (int j = 0; j < NBINS; ++j) { acc += bsh[j]; cdfb[j] = acc; }
        // top-equalization reproduces searchsorted clip at q > min(top_a, top_b)
        float T = fmaxf(cdfa[NBINS - 1], cdfb[NBINS - 1]);
        cdfa[NBINS - 1] = T;
        cdfb[NBINS - 1] = T;

        // sum over merged quantile intervals == sum of pairwise interval overlaps
        float loss = 0.0f, lo_a = 0.0f;
        #pragma unroll
        for (int i = 0; i < NBINS; ++i) {
            float hi_a = cdfa[i];
            float lo_b = 0.0f;
            #pragma unroll
            for (int j = 0; j < NBINS; ++j) {
                float hi_b = cdfb[j];
                float ov = fminf(hi_a, hi_b) - fmaxf(lo_a, lo_b);
                float w = (float)((i - j) * (i - j));
                loss += fmaxf(ov, 0.0f) * w;
                lo_b = hi_b;
            }
            lo_a = hi_a;
        }
        losses[gI] = loss;
    }
    __syncthreads();
    if (threadIdx.x == 0)
        out[0] = losses[0] + losses[1] + losses[2] + losses[3];
}

extern "C" void kernel_launch(void* const* d_in, const int* in_sizes, int n_in,
                              void* d_out, int out_size, void* d_ws, size_t ws_size,
                              hipStream_t stream) {
    const float* acts   = (const float*)d_in[0];
    const float* bary   = (const float*)d_in[1];
    const int*   labels = (const int*)d_in[2];
    float* outp  = (float*)d_out;
    float* parts = (float*)d_ws;           // [NH][NBLOCKS] = 327 KB, fully rewritten
    int N  = in_sizes[0];
    int n4 = N >> 2;

    wb_hist<<<NBLOCKS, TPB, 0, stream>>>((const f32x4*)acts, (const i32x4*)labels,
                                         acts, labels, parts, n4, N, NBLOCKS);
    wb_final<<<1, 1024, 0, stream>>>((const float4*)parts, bary, outp, NBLOCKS);
}